// Round 9
// baseline (181.619 us; speedup 1.0000x reference)
//
#include <hip/hip_runtime.h>
#include <hip/hip_bf16.h>
#include <math.h>

#define INPUT_DIM 256
#define OUT_DIM   256
#define NDEG      8                    // degree+1
#define KTOT      (INPUT_DIM * NDEG)   // 2048
#define NROWS     (16 * 2048)          // 32768

#define BM  128                        // block rows (featurize exactly once globally)
#define BK  64                         // 8 inputs * 8 degrees per K-chunk
#define NK  (KTOT / BK)                // 32
#define SUPER 4                        // chunks per super-step
#define NSUP  (NK / SUPER)             // 8
#define CHUNK_ELEMS 16384              // full-width B chunk: 256 o * 64 k

typedef __bf16 bf16x8 __attribute__((ext_vector_type(8)));
typedef float  f32x16 __attribute__((ext_vector_type(16)));

// ---------------------------------------------------------------------------
// Kernel 1: reorder coeffs C[i][o][d] (fp32) -> B pages (bf16). R11 layout:
// chunk-local input p = i&7 -> s = p>>1, h = p&1. Frag (kc,s,c,ni), lane
// (l31,h): dst = kc*16384 + (s*4+c)*1024 + ni*512 + h*256 + l31*8 + d
// ---------------------------------------------------------------------------
__global__ __launch_bounds__(256) void reorder_coeffs(const float* __restrict__ C,
                                                      __bf16* __restrict__ Bt) {
    int g = blockIdx.x * 256 + threadIdx.x;   // 65536 = 256 i * 256 o
    int i = g >> 8;
    int o = g & 255;
    const float4* src = (const float4*)(C + (size_t)i * (OUT_DIM * NDEG) + o * NDEG);
    float4 a = src[0];
    float4 b = src[1];
    bf16x8 v;
    v[0] = (__bf16)a.x; v[1] = (__bf16)a.y; v[2] = (__bf16)a.z; v[3] = (__bf16)a.w;
    v[4] = (__bf16)b.x; v[5] = (__bf16)b.y; v[6] = (__bf16)b.z; v[7] = (__bf16)b.w;
    int kc = i >> 3;
    int p  = i & 7;
    int s  = p >> 1;
    int hh = p & 1;
    int cc = o >> 6;
    int ni = (o >> 5) & 1;
    int l31 = o & 31;
    size_t dst = (size_t)kc * CHUNK_ELEMS + (s * 4 + cc) * 1024 + ni * 512 + hh * 256 + l31 * 8;
    *(bf16x8*)(Bt + dst) = v;   // 16B-aligned
}

// tanh + physicists' Hermite recurrence -> 8 degrees as bf16x8
__device__ __forceinline__ bf16x8 featurize(float xs) {
    float e = __expf(2.0f * xs);            // tanh(x)=1-2/(e^{2x}+1), robust all x
    float t = 1.0f - 2.0f / (e + 1.0f);
    bf16x8 v;
    float hm2 = 1.0f;                       // H_0
    float hm1 = 2.0f * t;                   // H_1
    v[0] = (__bf16)hm2;
    v[1] = (__bf16)hm1;
    #pragma unroll
    for (int d = 2; d < 8; ++d) {
        float h = 2.0f * t * hm1 - 2.0f * (float)(d - 1) * hm2;
        v[d] = (__bf16)h;
        hm2 = hm1; hm1 = h;
    }
    return v;
}

// lgkm-only barrier: each wave's own LDS ops complete before it signals --
// full producer/consumer requirement for the Alds dbuf. B/x loads target
// registers and carry compiler vmcnt waits at use; they stay in flight.
#define BARRIER() do {                                             \
    asm volatile("s_waitcnt lgkmcnt(0)" ::: "memory");             \
    __builtin_amdgcn_s_barrier();                                  \
    asm volatile("" ::: "memory");                                 \
} while (0)

// ---------------------------------------------------------------------------
// Kernel 2 (Round 18): producer/consumer wave specialization.
//  R10-R17 post-mortem: nine schedule variants all land 45-59us because every
//  wave is both producer (featurize VALU + ds_write) and consumer (ds_read +
//  MFMA): the MFMA cluster chains behind featurize via the in-order lgkmcnt,
//  and after any barrier the phase-identical waves want the SAME pipe first
//  -> MFMA/VALU/LDS serialize (3370 cyc/chunk vs 1082 MFMA). Fix: different
//  CODE per wave. Waves 0-7 = pure consumers (R11 compute, no featurize, no
//  ds_write -> lgkm waits cover only own reads). Waves 8-11 = pure producers
//  (featurize super S+1 into the dbuf, no MFMA). %4 round-robin puts
//  2 consumers + 1 producer per SIMD: consumers keep the matrix pipe fed
//  (1082 cyc/chunk) while producer VALU (~280 cyc/SIMD/chunk) issues in the
//  pipe-backpressure slots -- overlap by construction (AITER-style). setprio
//  around MFMA now has real role diversity (T5 prerequisite). One lgkm-drain
//  barrier per super; both paths execute 1+NSUP barriers. Producer slack per
//  super ~2x (x-latency + 16 featurize ~2100 cyc vs 4096 consumer).
// Block 768 thr / 12 waves (8 cons: 2mr x 4c, wave tile 64x64; 4 prod),
// tile 128x256, grid 256 = 1 block/CU, LDS 128 KB.
// ---------------------------------------------------------------------------
__global__ __launch_bounds__(768, 3) void hermite_mfma(const float* __restrict__ x,
                                                       const __bf16* __restrict__ Bt,
                                                       float* __restrict__ out) {
    // [buf][chunk-in-super cc*8192 + page j*1024 + m*8]; page = input (cc,j)
    __shared__ __align__(16) __bf16 Alds[2][SUPER * 8192];   // 128 KB

    const int tid  = threadIdx.x;
    const int bm   = blockIdx.x;       // 0..255
    const int wave = tid >> 6;         // 0..11

    if (wave < 8) {
        // =================== CONSUMER: ds_read A + BLOAD B + MFMA ===========
        const int mr   = wave >> 2;    // 0..1 : row half
        const int c    = wave & 3;     // 0..3 : column slice
        const int lane = tid & 63;
        const int l31  = lane & 31;
        const int h    = lane >> 5;

        // B pages for column slice c: frag(kc,s,ni) at
        //   Bt + kc*16384 + (s*4+c)*1024 + ni*512 + lane*8
        const __bf16* bbase = Bt + (size_t)c * 1024 + lane * 8;

        f32x16 acc[2][2] = {};
        bf16x8 bfr0[4][2];             // chunk B-frag buffer A (static names)
        bf16x8 bfr1[4][2];             // chunk B-frag buffer B

#define BLOAD(DST, KC)                                                       \
        if ((KC) < NK) {                                                     \
            const __bf16* g = bbase + (size_t)(KC) * CHUNK_ELEMS;            \
            _Pragma("unroll")                                                \
            for (int s = 0; s < 4; ++s) {                                    \
                DST[s][0] = *(const bf16x8*)(g + s * 4096);                  \
                DST[s][1] = *(const bf16x8*)(g + s * 4096 + 512);            \
            }                                                                \
        }

#define MFMA4(AF0, AF1, CURS)                                                \
        acc[0][0] = __builtin_amdgcn_mfma_f32_32x32x16_bf16(AF0, CURS[0], acc[0][0], 0, 0, 0); \
        acc[0][1] = __builtin_amdgcn_mfma_f32_32x32x16_bf16(AF0, CURS[1], acc[0][1], 0, 0, 0); \
        acc[1][0] = __builtin_amdgcn_mfma_f32_32x32x16_bf16(AF1, CURS[0], acc[1][0], 0, 0, 0); \
        acc[1][1] = __builtin_amdgcn_mfma_f32_32x32x16_bf16(AF1, CURS[1], acc[1][1], 0, 0, 0);

        // One chunk: 8 ds_read A-frags (reads only -> clean lgkm), prefetch
        // next chunk's B, then 16 MFMA under setprio.
#define CSTEP(KC, CC, CUR, NXT)                                              \
        {                                                                    \
            const __bf16* ab = &Alds[CB][(CC) * 8192 + mr * 512 + l31 * 8];  \
            bf16x8 a0 = *(const bf16x8*)(ab + (0 + h) * 1024);               \
            bf16x8 a1 = *(const bf16x8*)(ab + (0 + h) * 1024 + 256);         \
            bf16x8 a2 = *(const bf16x8*)(ab + (2 + h) * 1024);               \
            bf16x8 a3 = *(const bf16x8*)(ab + (2 + h) * 1024 + 256);         \
            bf16x8 a4 = *(const bf16x8*)(ab + (4 + h) * 1024);               \
            bf16x8 a5 = *(const bf16x8*)(ab + (4 + h) * 1024 + 256);         \
            bf16x8 a6 = *(const bf16x8*)(ab + (6 + h) * 1024);               \
            bf16x8 a7 = *(const bf16x8*)(ab + (6 + h) * 1024 + 256);         \
            BLOAD(NXT, (KC) + 1);                                            \
            __builtin_amdgcn_s_setprio(1);                                   \
            MFMA4(a0, a1, CUR[0]); MFMA4(a2, a3, CUR[1]);                    \
            MFMA4(a4, a5, CUR[2]); MFMA4(a6, a7, CUR[3]);                    \
            __builtin_amdgcn_s_setprio(0);                                   \
        }

        BLOAD(bfr0, 0);
        BARRIER();                     // matches producer prologue barrier

        #pragma unroll 2
        for (int S = 0; S < NSUP; ++S) {
            const int CB = S & 1;
            const int k0 = S * 4;
            CSTEP(k0 + 0, 0, bfr0, bfr1);
            CSTEP(k0 + 1, 1, bfr1, bfr0);
            CSTEP(k0 + 2, 2, bfr0, bfr1);
            CSTEP(k0 + 3, 3, bfr1, bfr0);
            BARRIER();
        }
#undef CSTEP
#undef MFMA4
#undef BLOAD

        // epilogue: 32x32 C/D col=lane&31, row=(reg&3)+8*(reg>>2)+4*h
        #pragma unroll
        for (int mi = 0; mi < 2; ++mi)
            #pragma unroll
            for (int ni = 0; ni < 2; ++ni) {
                #pragma unroll
                for (int r = 0; r < 16; ++r) {
                    int rl  = (r & 3) + 8 * (r >> 2) + 4 * h;
                    int row = bm * BM + mr * 64 + mi * 32 + rl;
                    out[(size_t)row * OUT_DIM + c * 64 + ni * 32 + l31] = acc[mi][ni][r];
                }
            }
    } else {
        // =================== PRODUCER: featurize -> Alds dbuf ===============
        // 4 waves = 256 threads; thread (m = row 0..127, g = 0..1) covers
        // inputs sup*32 + g*16 + {0..15}: exactly-once globally.
        const int ptid = tid - 512;
        const int m    = ptid & 127;
        const int g    = ptid >> 7;    // 0..1
        const float* xptr = x + (size_t)(bm * BM + m) * INPUT_DIM + g * 16;

#define PFEAT4(NB, J0, Q)                                                    \
        *(bf16x8*)(&Alds[NB][(g * 16 + (J0) + 0) * 1024 + m * 8]) = featurize(Q.x); \
        *(bf16x8*)(&Alds[NB][(g * 16 + (J0) + 1) * 1024 + m * 8]) = featurize(Q.y); \
        *(bf16x8*)(&Alds[NB][(g * 16 + (J0) + 2) * 1024 + m * 8]) = featurize(Q.z); \
        *(bf16x8*)(&Alds[NB][(g * 16 + (J0) + 3) * 1024 + m * 8]) = featurize(Q.w);

        {   // prologue: super 0 -> buf 0
            float4 q0 = *(const float4*)(xptr);
            float4 q1 = *(const float4*)(xptr + 4);
            float4 q2 = *(const float4*)(xptr + 8);
            float4 q3 = *(const float4*)(xptr + 12);
            PFEAT4(0, 0,  q0); PFEAT4(0, 4,  q1);
            PFEAT4(0, 8,  q2); PFEAT4(0, 12, q3);
        }
        BARRIER();

        for (int S = 0; S < NSUP; ++S) {
            if (S + 1 < NSUP) {
                const int NB = (S + 1) & 1;
                const float* xs = xptr + (S + 1) * 32;
                float4 q0 = *(const float4*)(xs);
                float4 q1 = *(const float4*)(xs + 4);
                float4 q2 = *(const float4*)(xs + 8);
                float4 q3 = *(const float4*)(xs + 12);
                PFEAT4(NB, 0,  q0); PFEAT4(NB, 4,  q1);
                PFEAT4(NB, 8,  q2); PFEAT4(NB, 12, q3);
            }
            BARRIER();
        }
#undef PFEAT4
    }
}

// ---------------------------------------------------------------------------
extern "C" void kernel_launch(void* const* d_in, const int* in_sizes, int n_in,
                              void* d_out, int out_size, void* d_ws, size_t ws_size,
                              hipStream_t stream) {
    const float* x = (const float*)d_in[0];          // [16,2048,256] fp32
    const float* C = (const float*)d_in[1];          // [256,256,8]  fp32
    float* out = (float*)d_out;                      // [16,2048,256] fp32
    __bf16* Bt = (__bf16*)d_ws;                      // paged [32][16384] bf16, 1 MB

    reorder_coeffs<<<dim3((INPUT_DIM * OUT_DIM) / 256), dim3(256), 0, stream>>>(C, Bt);
    hermite_mfma<<<dim3(NROWS / BM), dim3(768), 0, stream>>>(x, Bt, out);
}

// Round 10
// 123.467 us; speedup vs baseline: 1.4710x; 1.4710x over previous
//
#include <hip/hip_runtime.h>
#include <hip/hip_bf16.h>
#include <math.h>

#define INPUT_DIM 256
#define OUT_DIM   256
#define NDEG      8                    // degree+1
#define KTOT      (INPUT_DIM * NDEG)   // 2048
#define NROWS     (16 * 2048)          // 32768

#define BM  128                        // block rows
#define BN  128                        // block cols (R19: halved so 8-wave P/C fits regs)
#define BK  64                         // 8 inputs * 8 degrees per K-chunk
#define NK  (KTOT / BK)                // 32
#define SUPER 4                        // chunks per super-step
#define NSUP  (NK / SUPER)             // 8
#define CHUNK_ELEMS 16384              // full-width B chunk: 256 o * 64 k

typedef __bf16 bf16x8 __attribute__((ext_vector_type(8)));
typedef float  f32x16 __attribute__((ext_vector_type(16)));

// ---------------------------------------------------------------------------
// Kernel 1: reorder coeffs C[i][o][d] (fp32) -> B pages (bf16). R11 layout:
// chunk-local input p = i&7 -> s = p>>1, h = p&1. Frag (kc,s,c,ni), lane
// (l31,h): dst = kc*16384 + (s*4+c)*1024 + ni*512 + h*256 + l31*8 + d
// ---------------------------------------------------------------------------
__global__ __launch_bounds__(256) void reorder_coeffs(const float* __restrict__ C,
                                                      __bf16* __restrict__ Bt) {
    int g = blockIdx.x * 256 + threadIdx.x;   // 65536 = 256 i * 256 o
    int i = g >> 8;
    int o = g & 255;
    const float4* src = (const float4*)(C + (size_t)i * (OUT_DIM * NDEG) + o * NDEG);
    float4 a = src[0];
    float4 b = src[1];
    bf16x8 v;
    v[0] = (__bf16)a.x; v[1] = (__bf16)a.y; v[2] = (__bf16)a.z; v[3] = (__bf16)a.w;
    v[4] = (__bf16)b.x; v[5] = (__bf16)b.y; v[6] = (__bf16)b.z; v[7] = (__bf16)b.w;
    int kc = i >> 3;
    int p  = i & 7;
    int s  = p >> 1;
    int hh = p & 1;
    int cc = o >> 6;
    int ni = (o >> 5) & 1;
    int l31 = o & 31;
    size_t dst = (size_t)kc * CHUNK_ELEMS + (s * 4 + cc) * 1024 + ni * 512 + hh * 256 + l31 * 8;
    *(bf16x8*)(Bt + dst) = v;   // 16B-aligned
}

// tanh + physicists' Hermite recurrence -> 8 degrees as bf16x8
__device__ __forceinline__ bf16x8 featurize(float xs) {
    float e = __expf(2.0f * xs);            // tanh(x)=1-2/(e^{2x}+1), robust all x
    float t = 1.0f - 2.0f / (e + 1.0f);
    bf16x8 v;
    float hm2 = 1.0f;                       // H_0
    float hm1 = 2.0f * t;                   // H_1
    v[0] = (__bf16)hm2;
    v[1] = (__bf16)hm1;
    #pragma unroll
    for (int d = 2; d < 8; ++d) {
        float h = 2.0f * t * hm1 - 2.0f * (float)(d - 1) * hm2;
        v[d] = (__bf16)h;
        hm2 = hm1; hm1 = h;
    }
    return v;
}

// lgkm-only barrier: each wave's own LDS ops complete before it signals --
// full producer/consumer requirement for the Alds dbuf. B/x loads target
// registers and carry compiler vmcnt waits at use; they stay in flight.
#define BARRIER() do {                                             \
    asm volatile("s_waitcnt lgkmcnt(0)" ::: "memory");             \
    __builtin_amdgcn_s_barrier();                                  \
    asm volatile("" ::: "memory");                                 \
} while (0)

// ---------------------------------------------------------------------------
// Kernel 2 (Round 19): producer/consumer specialization, 8-wave (fits regs).
//  R18 post-mortem: 12-wave block -> >=3 waves/SIMD -> 170-reg hard cap
//  (512-entry/SIMD file, m69) < consumer's ~185 -> structural spill
//  (WRITE_SIZE 235 MB). Per-kernel allocation = union of branches, so every
//  wave pays consumer cost. Fix: tile 128x128, 8 waves = 4 consumers
//  (64x64 wave tile, R18 CSTEP unchanged) + 4 producers (R18 producer
//  unchanged). 2 waves/SIMD -> 256-reg cap; 2x185 = 370 <= 512/SIMD.
//  Role = (wave ^ (wave>>2)) & 1 -> exactly 1C+1P per SIMD under BOTH
//  candidate wave->SIMD pairings ({w,w+4} and {2k,2k+1}); within-role
//  index = wave>>1 under both. Consumer keeps the matrix pipe fed while
//  the co-resident producer's featurize VALU issues in pipe-backpressure
//  slots; setprio has true role diversity (T5 prerequisite). Producer
//  slack ~2x (1000 vs 2048 cyc/super). Costs: featurize x2 (bn pair),
//  B L2 256 MB total (unchanged). Grid 512 (bm=bx>>1, bn=bx&1: pair
//  shares x rows; x fits L3 so FETCH stays ~21 MB), 2 block-passes/CU.
// ---------------------------------------------------------------------------
__global__ __launch_bounds__(512, 2) void hermite_mfma(const float* __restrict__ x,
                                                       const __bf16* __restrict__ Bt,
                                                       float* __restrict__ out) {
    // [buf][chunk-in-super cc*8192 + page j*1024 + m*8]; page = input (cc,j)
    __shared__ __align__(16) __bf16 Alds[2][SUPER * 8192];   // 128 KB

    const int tid  = threadIdx.x;
    const int bx   = blockIdx.x;       // 0..511
    const int bm   = bx >> 1;          // 0..255 : row block
    const int bn   = bx & 1;           // 0..1   : col half
    const int wave = tid >> 6;         // 0..7
    const int lane = tid & 63;
    const int ridx = wave >> 1;        // within-role index (valid for both roles)

    if (((wave ^ (wave >> 2)) & 1) == 0) {
        // ========== CONSUMER (waves 0,2,5,7): ds_read A + BLOAD B + MFMA ====
        const int mr  = ridx >> 1;     // 0..1 : row half (64 rows)
        const int c   = bn * 2 + (ridx & 1);  // 0..3 : global column slice (64)
        const int l31 = lane & 31;
        const int h   = lane >> 5;

        // B pages for column slice c: frag(kc,s,ni) at
        //   Bt + kc*16384 + (s*4+c)*1024 + ni*512 + lane*8
        const __bf16* bbase = Bt + (size_t)c * 1024 + lane * 8;

        f32x16 acc[2][2] = {};
        bf16x8 bfr0[4][2];             // chunk B-frag buffer A (static names)
        bf16x8 bfr1[4][2];             // chunk B-frag buffer B

#define BLOAD(DST, KC)                                                       \
        if ((KC) < NK) {                                                     \
            const __bf16* g = bbase + (size_t)(KC) * CHUNK_ELEMS;            \
            _Pragma("unroll")                                                \
            for (int s = 0; s < 4; ++s) {                                    \
                DST[s][0] = *(const bf16x8*)(g + s * 4096);                  \
                DST[s][1] = *(const bf16x8*)(g + s * 4096 + 512);            \
            }                                                                \
        }

#define MFMA4(AF0, AF1, CURS)                                                \
        acc[0][0] = __builtin_amdgcn_mfma_f32_32x32x16_bf16(AF0, CURS[0], acc[0][0], 0, 0, 0); \
        acc[0][1] = __builtin_amdgcn_mfma_f32_32x32x16_bf16(AF0, CURS[1], acc[0][1], 0, 0, 0); \
        acc[1][0] = __builtin_amdgcn_mfma_f32_32x32x16_bf16(AF1, CURS[0], acc[1][0], 0, 0, 0); \
        acc[1][1] = __builtin_amdgcn_mfma_f32_32x32x16_bf16(AF1, CURS[1], acc[1][1], 0, 0, 0);

        // One chunk: 8 ds_read A-frags (reads only -> clean lgkm), prefetch
        // next chunk's B, then 16 MFMA under setprio.
#define CSTEP(KC, CC, CUR, NXT)                                              \
        {                                                                    \
            const __bf16* ab = &Alds[CB][(CC) * 8192 + mr * 512 + l31 * 8];  \
            bf16x8 a0 = *(const bf16x8*)(ab + (0 + h) * 1024);               \
            bf16x8 a1 = *(const bf16x8*)(ab + (0 + h) * 1024 + 256);         \
            bf16x8 a2 = *(const bf16x8*)(ab + (2 + h) * 1024);               \
            bf16x8 a3 = *(const bf16x8*)(ab + (2 + h) * 1024 + 256);         \
            bf16x8 a4 = *(const bf16x8*)(ab + (4 + h) * 1024);               \
            bf16x8 a5 = *(const bf16x8*)(ab + (4 + h) * 1024 + 256);         \
            bf16x8 a6 = *(const bf16x8*)(ab + (6 + h) * 1024);               \
            bf16x8 a7 = *(const bf16x8*)(ab + (6 + h) * 1024 + 256);         \
            BLOAD(NXT, (KC) + 1);                                            \
            __builtin_amdgcn_s_setprio(1);                                   \
            MFMA4(a0, a1, CUR[0]); MFMA4(a2, a3, CUR[1]);                    \
            MFMA4(a4, a5, CUR[2]); MFMA4(a6, a7, CUR[3]);                    \
            __builtin_amdgcn_s_setprio(0);                                   \
        }

        BLOAD(bfr0, 0);
        BARRIER();                     // matches producer prologue barrier

        #pragma unroll 2
        for (int S = 0; S < NSUP; ++S) {
            const int CB = S & 1;
            const int k0 = S * 4;
            CSTEP(k0 + 0, 0, bfr0, bfr1);
            CSTEP(k0 + 1, 1, bfr1, bfr0);
            CSTEP(k0 + 2, 2, bfr0, bfr1);
            CSTEP(k0 + 3, 3, bfr1, bfr0);
            BARRIER();
        }
#undef CSTEP
#undef MFMA4
#undef BLOAD

        // epilogue: 32x32 C/D col=lane&31, row=(reg&3)+8*(reg>>2)+4*h
        #pragma unroll
        for (int mi = 0; mi < 2; ++mi)
            #pragma unroll
            for (int ni = 0; ni < 2; ++ni) {
                #pragma unroll
                for (int r = 0; r < 16; ++r) {
                    int rl  = (r & 3) + 8 * (r >> 2) + 4 * h;
                    int row = bm * BM + mr * 64 + mi * 32 + rl;
                    out[(size_t)row * OUT_DIM + c * 64 + ni * 32 + l31] = acc[mi][ni][r];
                }
            }
    } else {
        // ========== PRODUCER (waves 1,3,4,6): featurize -> Alds dbuf ========
        // 4 waves = 256 threads; thread (m = row 0..127, g = 0..1) covers
        // inputs sup*32 + g*16 + {0..15}: exactly-once per block.
        const int ptid = ridx * 64 + lane;   // 0..255
        const int m    = ptid & 127;
        const int g    = ptid >> 7;    // 0..1
        const float* xptr = x + (size_t)(bm * BM + m) * INPUT_DIM + g * 16;

#define PFEAT4(NB, J0, Q)                                                    \
        *(bf16x8*)(&Alds[NB][(g * 16 + (J0) + 0) * 1024 + m * 8]) = featurize(Q.x); \
        *(bf16x8*)(&Alds[NB][(g * 16 + (J0) + 1) * 1024 + m * 8]) = featurize(Q.y); \
        *(bf16x8*)(&Alds[NB][(g * 16 + (J0) + 2) * 1024 + m * 8]) = featurize(Q.z); \
        *(bf16x8*)(&Alds[NB][(g * 16 + (J0) + 3) * 1024 + m * 8]) = featurize(Q.w);

        {   // prologue: super 0 -> buf 0
            float4 q0 = *(const float4*)(xptr);
            float4 q1 = *(const float4*)(xptr + 4);
            float4 q2 = *(const float4*)(xptr + 8);
            float4 q3 = *(const float4*)(xptr + 12);
            PFEAT4(0, 0,  q0); PFEAT4(0, 4,  q1);
            PFEAT4(0, 8,  q2); PFEAT4(0, 12, q3);
        }
        BARRIER();

        for (int S = 0; S < NSUP; ++S) {
            if (S + 1 < NSUP) {
                const int NB = (S + 1) & 1;
                const float* xs = xptr + (S + 1) * 32;
                float4 q0 = *(const float4*)(xs);
                float4 q1 = *(const float4*)(xs + 4);
                float4 q2 = *(const float4*)(xs + 8);
                float4 q3 = *(const float4*)(xs + 12);
                PFEAT4(NB, 0,  q0); PFEAT4(NB, 4,  q1);
                PFEAT4(NB, 8,  q2); PFEAT4(NB, 12, q3);
            }
            BARRIER();
        }
#undef PFEAT4
    }
}

// ---------------------------------------------------------------------------
extern "C" void kernel_launch(void* const* d_in, const int* in_sizes, int n_in,
                              void* d_out, int out_size, void* d_ws, size_t ws_size,
                              hipStream_t stream) {
    const float* x = (const float*)d_in[0];          // [16,2048,256] fp32
    const float* C = (const float*)d_in[1];          // [256,256,8]  fp32
    float* out = (float*)d_out;                      // [16,2048,256] fp32
    __bf16* Bt = (__bf16*)d_ws;                      // paged [32][16384] bf16, 1 MB

    reorder_coeffs<<<dim3((INPUT_DIM * OUT_DIM) / 256), dim3(256), 0, stream>>>(C, Bt);
    hermite_mfma<<<dim3((NROWS / BM) * (OUT_DIM / BN)), dim3(512), 0, stream>>>(x, Bt, out);
}